// Round 1
// baseline (1924.838 us; speedup 1.0000x reference)
//
#include <hip/hip_runtime.h>
#include <math.h>

#define BATCH 8192
#define NG 8
#define NE 512
#define ED 256

// ---- output layout (flat f32, reference tuple order) ----
static constexpr long long QA    = 2LL * BATCH * NG * ED;   // 33554432 (quantized_all / enc_emb)
static constexpr long long OHSZ  = (long long)NG * 2 * BATCH * NE; // 67108864
static constexpr long long GBK   = (long long)NG * BATCH * NE;     // 33554432
static constexpr long long O_VQ    = 0;
static constexpr long long O_PAIR  = 1;
static constexpr long long O_QUANT = 2;
static constexpr long long O_PERP  = 2 + QA;
static constexpr long long O_ENC   = 3 + QA;
static constexpr long long O_OH    = 3 + 2 * QA;
static constexpr long long O_D0    = O_OH + OHSZ;
static constexpr long long O_D1    = O_D0 + GBK;

// ---- workspace layout (bytes) ----
// wsidx: int[2][NG][BATCH]    @ 0         (524288)
// hist:  int[2][NG][NE]       @ 524288    (32768)
// nshared: int[NG]            @ 557056    (32)
// sums:  float[2][NG]         @ 557088    (64)
// esq:   float[NG][NE]        @ 557152    (16384)
#define WS_HIST    524288
#define WS_NSHARED 557056
#define WS_SUMS    557088
#define WS_ESQ     557152

// ------------------------------------------------------------------
// esq[g][k] = sum_d emb[g][k][d]^2   (one wave per row)
__global__ void esq_kernel(const float* __restrict__ emb, float* __restrict__ esq) {
    const int row  = blockIdx.x * 4 + (threadIdx.x >> 6);   // 0..4095
    const int lane = threadIdx.x & 63;
    const float4 v = *(const float4*)&emb[(size_t)row * ED + lane * 4];
    float s = v.x * v.x + v.y * v.y + v.z * v.z + v.w * v.w;
    for (int off = 32; off; off >>= 1) s += __shfl_xor(s, off);
    if (lane == 0) esq[row] = s;
}

// ------------------------------------------------------------------
// Fused distance GEMM + row argmin.  One block: 32 rows x all 512 codes.
// 256 threads = 4 rowgrps(8 rows) x 64 colgrps(8 cols, stride 64).
__global__ __launch_bounds__(256) void dist_kernel(
        const float* __restrict__ x0, const float* __restrict__ x1,
        const float* __restrict__ emb, const int* __restrict__ labels,
        const float* __restrict__ esq, int* __restrict__ wsidx,
        float* __restrict__ out) {
    __shared__ float As[16][32];
    __shared__ float Bs[16][516];   // stride 516 breaks staging bank conflicts

    const int tid = threadIdx.x;
    const int g = blockIdx.y, inp = blockIdx.z;
    const int b0 = blockIdx.x * 32;
    const float* __restrict__ X = inp ? x1 : x0;
    const int rowgrp = tid >> 6;    // wave id: all lanes of a wave share rowgrp
    const int colgrp = tid & 63;

    float acc[8][8];
    float xs[8];
#pragma unroll
    for (int r = 0; r < 8; ++r) {
        xs[r] = 0.f;
#pragma unroll
        for (int j = 0; j < 8; ++j) acc[r][j] = 0.f;
    }

    for (int kc = 0; kc < ED; kc += 16) {
        // stage A tile: 32 rows x 16 k
        if (tid < 128) {
            const int r = tid >> 2, p = tid & 3;
            const float4 v = *(const float4*)&X[((size_t)(b0 + r) * NG + g) * ED + kc + p * 4];
            As[p * 4 + 0][r] = v.x; As[p * 4 + 1][r] = v.y;
            As[p * 4 + 2][r] = v.z; As[p * 4 + 3][r] = v.w;
        }
        // stage B tile: 512 codes x 16 k (transposed into [k][code])
#pragma unroll
        for (int s = 0; s < 8; ++s) {
            const int f = tid + 256 * s;
            const int k = f >> 2, p = f & 3;
            const float4 v = *(const float4*)&emb[((size_t)g * NE + k) * ED + kc + p * 4];
            Bs[p * 4 + 0][k] = v.x; Bs[p * 4 + 1][k] = v.y;
            Bs[p * 4 + 2][k] = v.z; Bs[p * 4 + 3][k] = v.w;
        }
        __syncthreads();
#pragma unroll
        for (int kk = 0; kk < 16; ++kk) {
            const float4 a0 = *(const float4*)&As[kk][rowgrp * 8];
            const float4 a1 = *(const float4*)&As[kk][rowgrp * 8 + 4];
            const float a[8] = {a0.x, a0.y, a0.z, a0.w, a1.x, a1.y, a1.z, a1.w};
            float bb[8];
#pragma unroll
            for (int j = 0; j < 8; ++j) bb[j] = Bs[kk][colgrp + 64 * j];
#pragma unroll
            for (int r = 0; r < 8; ++r) {
                xs[r] += a[r] * a[r];
#pragma unroll
                for (int j = 0; j < 8; ++j) acc[r][j] += a[r] * bb[j];
            }
        }
        __syncthreads();
    }

    // epilogue: d = |x|^2 + |e|^2 - 2 x.e ; write d; lexicographic argmin
    float eq[8];
#pragma unroll
    for (int j = 0; j < 8; ++j) eq[j] = esq[g * NE + colgrp + 64 * j];
    float* __restrict__ dbase = out + (inp ? O_D1 : O_D0);

#pragma unroll
    for (int r = 0; r < 8; ++r) {
        const int brow = b0 + rowgrp * 8 + r;
        float* __restrict__ drow = dbase + ((size_t)g * BATCH + brow) * NE;
        float mv = 3.402823466e38f;
        int mi = 0;
#pragma unroll
        for (int j = 0; j < 8; ++j) {
            const float dv = xs[r] + eq[j] - 2.0f * acc[r][j];
            drow[colgrp + 64 * j] = dv;
            if (dv < mv) { mv = dv; mi = colgrp + 64 * j; }  // cols ascend with j
        }
        // wave-wide (value, index) lexicographic min => first-occurrence argmin
        for (int off = 32; off; off >>= 1) {
            const float ov = __shfl_xor(mv, off);
            const int   oi = __shfl_xor(mi, off);
            if (ov < mv || (ov == mv && oi < mi)) { mv = ov; mi = oi; }
        }
        if (colgrp == 0) {
            const int lab = labels[g * BATCH + brow];
            wsidx[((size_t)inp * NG + g) * BATCH + brow] = (lab > -1) ? lab : mi;
        }
    }
}

// ------------------------------------------------------------------
// one-hot scatter + per-(i,g) histograms + shared-row counts
__global__ void scatter_kernel(const int* __restrict__ wsidx, const int* __restrict__ labels,
                               float* __restrict__ out, int* __restrict__ hist,
                               int* __restrict__ nshared) {
    __shared__ int lh[NE];
    __shared__ int sc;
    const int tid = threadIdx.x;
    lh[tid] = 0; lh[tid + 256] = 0;
    if (tid == 0) sc = 0;
    __syncthreads();

    const int n = blockIdx.x * 256 + tid;   // 0..131071; one block = one (i,g) slice chunk
    const int i = n >> 16;
    const int g = (n >> 13) & 7;
    const int b = n & 8191;
    const int idx = wsidx[n];
    out[O_OH + (((size_t)g * 2 + i) * BATCH + b) * NE + idx] = 1.0f;
    atomicAdd(&lh[idx], 1);
    if (i == 0) {
        if (labels[g * BATCH + b] > -1) atomicAdd(&sc, 1);
    }
    __syncthreads();
    atomicAdd(&hist[(size_t)(i * NG + g) * NE + tid], lh[tid]);
    atomicAdd(&hist[(size_t)(i * NG + g) * NE + tid + 256], lh[tid + 256]);
    if (tid == 0 && i == 0) atomicAdd(&nshared[g], sc);
}

// ------------------------------------------------------------------
// gather q=emb[idx], write quantized_all (st) + enc_embeddings_all, masked SSE
__global__ void lossgather_kernel(const float* __restrict__ x0, const float* __restrict__ x1,
                                  const float* __restrict__ emb, const int* __restrict__ wsidx,
                                  const int* __restrict__ labels, float* __restrict__ out,
                                  float* __restrict__ sums) {
    const int tid = threadIdx.x;
    const int g = blockIdx.y, i = blockIdx.z;
    const int b = blockIdx.x * 4 + (tid >> 6);
    const int c = tid & 63;
    const float* __restrict__ X = i ? x1 : x0;

    const int idx = wsidx[((size_t)i * NG + g) * BATCH + b];
    const float4 xv = *(const float4*)&X[((size_t)b * NG + g) * ED + c * 4];
    const float4 qv = *(const float4*)&emb[((size_t)g * NE + idx) * ED + c * 4];

    // straight-through forward: x + (q - x), matching reference rounding
    float4 st;
    st.x = xv.x + (qv.x - xv.x);
    st.y = xv.y + (qv.y - xv.y);
    st.z = xv.z + (qv.z - xv.z);
    st.w = xv.w + (qv.w - xv.w);
    *(float4*)&out[O_QUANT + (((size_t)i * BATCH + b) * NG + g) * ED + c * 4] = st;
    *(float4*)&out[O_ENC + (((size_t)i * NG + g) * BATCH + b) * ED + c * 4] = qv;

    float s = 0.f;
    if (labels[g * BATCH + b] > -1) {
        const float dx = qv.x - xv.x, dy = qv.y - xv.y, dz = qv.z - xv.z, dw = qv.w - xv.w;
        s = dx * dx + dy * dy + dz * dz + dw * dw;
    }
    for (int off = 32; off; off >>= 1) s += __shfl_xor(s, off);
    __shared__ float wsum[4];
    if ((tid & 63) == 0) wsum[tid >> 6] = s;
    __syncthreads();
    if (tid == 0) atomicAdd(&sums[i * NG + g], wsum[0] + wsum[1] + wsum[2] + wsum[3]);
}

// ------------------------------------------------------------------
__global__ void finalize_kernel(const float* __restrict__ sums, const int* __restrict__ hist,
                                const int* __restrict__ nshared, float* __restrict__ out) {
    const int tid = threadIdx.x;
    __shared__ double spg[16];
    if (tid < 16) {
        double a = 0.0;
        for (int k = 0; k < NE; ++k) {
            const double p = (double)hist[tid * NE + k] / (double)BATCH;
            a += p * log(p + 1e-10);
        }
        spg[tid] = a;
    }
    __syncthreads();
    if (tid == 0) {
        double vq = 0.0, pp = 0.0;
        for (int g = 0; g < NG; ++g) {
            const double denom = (double)nshared[g] * (double)ED;
            vq += 0.625 * ((double)sums[g] + (double)sums[NG + g]) / denom;
            pp += 0.5 * (exp(-spg[g]) + exp(-spg[NG + g]));
        }
        out[O_VQ]   = (float)(vq / NG);
        out[O_PAIR] = 0.0f;
        out[O_PERP] = (float)(pp / NG);
    }
}

// ------------------------------------------------------------------
extern "C" void kernel_launch(void* const* d_in, const int* in_sizes, int n_in,
                              void* d_out, int out_size, void* d_ws, size_t ws_size,
                              hipStream_t stream) {
    (void)in_sizes; (void)n_in; (void)out_size; (void)ws_size;
    const float* x0     = (const float*)d_in[0];
    const float* x1     = (const float*)d_in[1];
    const float* emb    = (const float*)d_in[2];
    const int*   labels = (const int*)d_in[3];
    float* out = (float*)d_out;
    char*  ws  = (char*)d_ws;

    int*   wsidx   = (int*)ws;
    int*   hist    = (int*)(ws + WS_HIST);
    int*   nshared = (int*)(ws + WS_NSHARED);
    float* sums    = (float*)(ws + WS_SUMS);
    float* esq     = (float*)(ws + WS_ESQ);

    hipMemsetAsync(ws + WS_HIST, 0, 32768 + 32 + 64, stream);
    hipMemsetAsync(out + O_OH, 0, (size_t)OHSZ * sizeof(float), stream);

    esq_kernel<<<NG * NE / 4, 256, 0, stream>>>(emb, esq);
    dist_kernel<<<dim3(BATCH / 32, NG, 2), 256, 0, stream>>>(x0, x1, emb, labels, esq, wsidx, out);
    scatter_kernel<<<2 * NG * BATCH / 256, 256, 0, stream>>>(wsidx, labels, out, hist, nshared);
    lossgather_kernel<<<dim3(BATCH / 4, NG, 2), 256, 0, stream>>>(x0, x1, emb, wsidx, labels, out, sums);
    finalize_kernel<<<1, 256, 0, stream>>>(sums, hist, nshared, out);
}